// Round 4
// baseline (301.848 us; speedup 1.0000x reference)
//
#include <hip/hip_runtime.h>

// DeepseekV3MoEToA2AAdapter: T=2048 tokens, H=1024, E=8, I=1408, top-2.
// fp32 I/O. LDS-transpose weight cast -> bf16 [E][N][K]; atomic-free router;
// 256-thread 4-wave MFMA GEMMs, BM=64 tiles (2x independent blocks vs BM=128:
// 1408 gateup / 2048 down working blocks -> latency hiding via block overlap);
// non-atomic split-K down + 4-way combine.
#define T_TOK 2048
#define HDIM  1024
#define NEXP  8
#define IDIM  1408

#define BM 64
#define BN 64
#define BK 32
#define KPAD 40     // bf16 elems; 80 B rows, 16B-aligned; frag reads 2-way (free)
#define GU_MT 32    // ceil(2048 / BM) m-slots
#define DN_MT 32
#define GU_NT 22    // IDIM / BN
#define DN_NT 16    // HDIM / BN
#define DK_HALF 704 // IDIM / 2 (split-K for down); 22 BK=32 steps

typedef __attribute__((ext_vector_type(8))) short bf16x8;
typedef __attribute__((ext_vector_type(4))) float f32x4;

static __device__ __forceinline__ unsigned short f2bf(float f) {
    union { float f; unsigned u; } a; a.f = f;
    return (unsigned short)((a.u + 0x7fffu + ((a.u >> 16) & 1u)) >> 16);
}

// ------------------------------------------- router pass 1: compute ---------
// One wave per token; fp64 ladder (robust top-2 ordering); fused x->bf16.
__global__ __launch_bounds__(256) void router_compute_kernel(
    const float* __restrict__ x,        // [T, H]
    const float* __restrict__ rw,       // [H, E]
    int*   __restrict__ sel,            // [T]
    float* __restrict__ w1arr,          // [T]
    unsigned short* __restrict__ xb)    // [T, H] bf16
{
    __shared__ float rwT[NEXP][HDIM];   // 32 KB
    const int tid = threadIdx.x;
#pragma unroll
    for (int p = 0; p < 4; ++p) {
        const int h = tid + 256 * p;
        const float4 a = *(const float4*)(rw + (size_t)h * 8);
        const float4 b = *(const float4*)(rw + (size_t)h * 8 + 4);
        rwT[0][h] = a.x; rwT[1][h] = a.y; rwT[2][h] = a.z; rwT[3][h] = a.w;
        rwT[4][h] = b.x; rwT[5][h] = b.y; rwT[6][h] = b.z; rwT[7][h] = b.w;
    }
    __syncthreads();

    const int wave = (blockIdx.x * blockDim.x + threadIdx.x) >> 6;
    const int lane = threadIdx.x & 63;
    if (wave >= T_TOK) return;
    const int t = wave;

    float xr[16];
    const float* xp = x + (size_t)t * HDIM;
#pragma unroll
    for (int i = 0; i < 16; ++i) xr[i] = xp[lane + 64 * i];

    unsigned short* xbp = xb + (size_t)t * HDIM;
#pragma unroll
    for (int i = 0; i < 16; ++i) xbp[lane + 64 * i] = f2bf(xr[i]);

    double logits[NEXP];
#pragma unroll
    for (int e = 0; e < NEXP; ++e) {
        double s = 0.0;
#pragma unroll
        for (int i = 0; i < 16; ++i)
            s += (double)xr[i] * (double)rwT[e][lane + 64 * i];
#pragma unroll
        for (int off = 32; off > 0; off >>= 1)
            s += __shfl_down(s, off, 64);
        logits[e] = s;
    }

    if (lane == 0) {
        int e1 = 0;
        for (int e = 1; e < NEXP; ++e) if (logits[e] > logits[e1]) e1 = e;
        int e2 = -1;
        for (int e = 0; e < NEXP; ++e) {
            if (e == e1) continue;
            if (e2 < 0 || logits[e] > logits[e2]) e2 = e;
        }
        const double w1 = 1.0 / (1.0 + exp(logits[e2] - logits[e1]));
        sel[t]   = e1 | (e2 << 8);
        w1arr[t] = (float)w1;
    }
}

// ------------------------------------------- router pass 2: scatter ---------
__global__ __launch_bounds__(1024) void router_scatter_kernel(
    const int* __restrict__ sel, const float* __restrict__ w1arr,
    int* __restrict__ counts,
    int* __restrict__ tok_list, float* __restrict__ wgt_list,
    int* __restrict__ row_list)
{
    __shared__ int cnt[NEXP];
    const int tid = threadIdx.x;
    if (tid < NEXP) cnt[tid] = 0;
    __syncthreads();
    for (int t = tid; t < T_TOK; t += 1024) {
        const int s  = sel[t];
        const int e1 = s & 255, e2 = s >> 8;
        const float w1 = w1arr[t];
        const int p1 = atomicAdd(&cnt[e1], 1);
        tok_list[e1 * T_TOK + p1] = t;
        wgt_list[e1 * T_TOK + p1] = w1;
        row_list[e1 * T_TOK + p1] = 2 * t;
        const int p2 = atomicAdd(&cnt[e2], 1);
        tok_list[e2 * T_TOK + p2] = t;
        wgt_list[e2 * T_TOK + p2] = 1.0f - w1;
        row_list[e2 * T_TOK + p2] = 2 * t + 1;
    }
    __syncthreads();
    if (tid < NEXP) counts[tid] = cnt[tid];
}

// ---------------------- weight cast+transpose via LDS (coalesced writes) ----
__global__ __launch_bounds__(256) void wtrans_all_kernel(
    const float* __restrict__ gw, const float* __restrict__ uw,
    const float* __restrict__ dw,
    unsigned short* __restrict__ gwt, unsigned short* __restrict__ uwt,
    unsigned short* __restrict__ dwt)
{
    const int z  = blockIdx.z;
    const int bx = blockIdx.x;          // 0..175
    const float* src; unsigned short* dst; int K, N, kb, nb;
    if (z < 16) {
        K = HDIM; N = IDIM;
        const int e = z & 7;
        src = (z < 8 ? gw : uw) + (size_t)e * K * N;
        dst = (z < 8 ? gwt : uwt) + (size_t)e * (size_t)N * K;
        nb = bx % 11; kb = bx / 11;     // 11 n-tiles x 16 k-tiles
    } else {
        K = IDIM; N = HDIM;
        const int e = z - 16;
        src = dw + (size_t)e * K * N;
        dst = dwt + (size_t)e * (size_t)N * K;
        nb = bx & 7; kb = bx >> 3;      // 8 n-tiles x 22 k-tiles
    }
    const int k0 = kb * 64;
    const int n0 = nb * 128;

    __shared__ unsigned short tb[128][66];   // [n][k], +2 pad -> 132 B rows

    const int tid = threadIdx.x;
    const int lk = tid >> 5;            // 0..7 (k sub-row)
    const int ln = (tid & 31) * 4;      // 0..124 (n)
#pragma unroll
    for (int r = 0; r < 8; ++r) {
        const int k = r * 8 + lk;
        const float4 v = *(const float4*)(src + (size_t)(k0 + k) * N + n0 + ln);
        tb[ln + 0][k] = f2bf(v.x);
        tb[ln + 1][k] = f2bf(v.y);
        tb[ln + 2][k] = f2bf(v.z);
        tb[ln + 3][k] = f2bf(v.w);
    }
    __syncthreads();

    const int wn = tid >> 3;            // 0..31 (n sub-row)
    const int wk = (tid & 7) * 8;       // 0..56 (k chunk)
#pragma unroll
    for (int p = 0; p < 4; ++p) {
        const int n = p * 32 + wn;
        const unsigned* rp = (const unsigned*)&tb[n][wk];  // 4 B aligned
        uint4 o;
        o.x = rp[0]; o.y = rp[1]; o.z = rp[2]; o.w = rp[3];
        *(uint4*)(dst + (size_t)(n0 + n) * K + k0 + wk) = o;
    }
}

// -------------------------------------------------- fused gate+up GEMM -----
// BM=64: 1408 working blocks (5.5/CU). 4 waves, wave tile 32x32 (x2 matrices).
// LDS ~16 KB -> residency bounded by work supply, not LDS.
__global__ __launch_bounds__(256) void gateup_kernel(
    const unsigned short* __restrict__ xb,    // [T,H] bf16
    const unsigned short* __restrict__ gwt,   // [E][I][H] bf16
    const unsigned short* __restrict__ uwt,   // [E][I][H] bf16
    const float* __restrict__ gb, const float* __restrict__ ub,
    const int* __restrict__ counts,
    const int* __restrict__ tok_list,
    const int* __restrict__ row_list,
    unsigned short* __restrict__ act)         // [2T, IDIM] bf16
{
    const int flat = blockIdx.x;
    const int xcd  = flat & 7;
    const int q    = flat >> 3;
    const int mt   = q & (GU_MT - 1);
    const int slot = q / GU_MT;
    const int P    = slot * 8 + xcd;   // 0..175 = (e, nt), fixed XCD per (e,nt)
    const int e    = P / GU_NT;
    const int nt   = P % GU_NT;
    const int n_e  = counts[e];
    const int m0   = mt * BM;
    if (m0 >= n_e) return;
    const int n0 = nt * BN;

    const unsigned short* gwp = gwt + (size_t)e * IDIM * HDIM;
    const unsigned short* uwp = uwt + (size_t)e * IDIM * HDIM;
    const float* gbp = gb + (size_t)e * IDIM;
    const float* ubp = ub + (size_t)e * IDIM;

    __shared__ unsigned short As[BM][KPAD];   // 5 KB
    __shared__ unsigned short Bg[BN][KPAD];   // 5 KB
    __shared__ unsigned short Bu[BN][KPAD];   // 5 KB
    __shared__ int gr_lds[BM];
    __shared__ int or_lds[BM];

    const int tid = threadIdx.x;
    const int base = e * T_TOK;
    if (tid < BM) {
        const int m = m0 + tid;
        int g = -1, o = -1;
        if (m < n_e) { g = tok_list[base + m]; o = row_list[base + m]; }
        gr_lds[tid] = g; or_lds[tid] = o;
    }
    __syncthreads();

    // staging: 64 rows x 4 chunks of 8 bf16 = 256 threads; each thread loads
    // one A chunk, one Bg chunk, one Bu chunk per K-step.
    const int ar = tid >> 2;
    const int ac = (tid & 3) * 8;
    const int arow = gr_lds[ar];
    const unsigned short* ap = xb + (size_t)(arow < 0 ? 0 : arow) * HDIM + ac;
    unsigned short* Adst = &As[0][0] + ar * KPAD + ac;
    const unsigned short* gsrc = gwp + (size_t)(n0 + ar) * HDIM + ac;
    const unsigned short* usrc = uwp + (size_t)(n0 + ar) * HDIM + ac;
    unsigned short* Gdst = &Bg[0][0] + ar * KPAD + ac;
    unsigned short* Udst = &Bu[0][0] + ar * KPAD + ac;

    const int wv = tid >> 6, lane = tid & 63;
    const int wm = (wv & 1) * 32, wn = (wv >> 1) * 32;
    const int l16 = lane & 15, quad = lane >> 4;

    f32x4 accg[2][2], accu[2][2];
    const f32x4 zero = {0.0f, 0.0f, 0.0f, 0.0f};
#pragma unroll
    for (int i = 0; i < 2; ++i)
#pragma unroll
        for (int j = 0; j < 2; ++j) { accg[i][j] = zero; accu[i][j] = zero; }

    uint4 PA = {0, 0, 0, 0}, PG, PU;
    if (arow >= 0) PA = *(const uint4*)(ap);
    PG = *(const uint4*)(gsrc);
    PU = *(const uint4*)(usrc);

    for (int k0 = 0; k0 < HDIM; k0 += BK) {
        __syncthreads();
        *(uint4*)Adst = PA;
        *(uint4*)Gdst = PG;
        *(uint4*)Udst = PU;
        __syncthreads();

        const int kn = k0 + BK;
        if (kn < HDIM) {
            if (arow >= 0) PA = *(const uint4*)(ap + kn);
            PG = *(const uint4*)(gsrc + kn);
            PU = *(const uint4*)(usrc + kn);
        }

        bf16x8 af[2], bgf[2], buf_[2];
#pragma unroll
        for (int i = 0; i < 2; ++i)
            af[i] = *(const bf16x8*)&As[wm + i * 16 + l16][quad * 8];
#pragma unroll
        for (int j = 0; j < 2; ++j) {
            bgf[j]  = *(const bf16x8*)&Bg[wn + j * 16 + l16][quad * 8];
            buf_[j] = *(const bf16x8*)&Bu[wn + j * 16 + l16][quad * 8];
        }
#pragma unroll
        for (int i = 0; i < 2; ++i)
#pragma unroll
            for (int j = 0; j < 2; ++j) {
                accg[i][j] = __builtin_amdgcn_mfma_f32_16x16x32_bf16(
                    af[i], bgf[j], accg[i][j], 0, 0, 0);
                accu[i][j] = __builtin_amdgcn_mfma_f32_16x16x32_bf16(
                    af[i], buf_[j], accu[i][j], 0, 0, 0);
            }
    }

    // epilogue: silu(g)*u -> bf16 act
#pragma unroll
    for (int j = 0; j < 2; ++j) {
        const int nl = n0 + wn + j * 16 + l16;
        const float gbv = gbp[nl];
        const float ubv = ubp[nl];
#pragma unroll
        for (int i = 0; i < 2; ++i) {
#pragma unroll
            for (int ii = 0; ii < 4; ++ii) {
                const int ml = wm + i * 16 + quad * 4 + ii;
                const int orow = or_lds[ml];
                if (orow >= 0) {
                    const float g = accg[i][j][ii] + gbv;
                    const float uu = accu[i][j][ii] + ubv;
                    act[(size_t)orow * IDIM + nl] =
                        f2bf(g * uu / (1.0f + __expf(-g)));
                }
            }
        }
    }
}

// ------------------------------------------------------- down-proj GEMM ----
// Split-K=2, NON-ATOMIC; BM=64 -> 2048 working blocks (8/CU, full occupancy).
__global__ __launch_bounds__(256) void down_kernel(
    const unsigned short* __restrict__ act,   // [2T, IDIM] bf16
    const unsigned short* __restrict__ dwt,   // [E][H][I] bf16
    const float* __restrict__ db,
    const int* __restrict__ counts,
    const float* __restrict__ wgt_list,
    const int* __restrict__ row_list,
    float* __restrict__ y2)                   // [2][2T, HDIM] fp32
{
    const int flat = blockIdx.x;
    const int xcd  = flat & 7;
    const int q    = flat >> 3;
    const int mt   = q & (DN_MT - 1);
    const int slot = q / DN_MT;
    const int P    = slot * 8 + xcd;   // 0..255 = (sk, e, nt)
    const int sk   = P & 1;
    const int en   = P >> 1;
    const int e    = en >> 4;
    const int nt   = en & 15;
    const int n_e  = counts[e];
    const int m0   = mt * BM;
    if (m0 >= n_e) return;
    const int n0 = nt * BN;
    const int ks = sk * DK_HALF;
    float* y2s = y2 + (size_t)sk * 2 * T_TOK * HDIM;

    const unsigned short* dwp = dwt + (size_t)e * HDIM * IDIM;
    const float* dbp = db + (size_t)e * HDIM;

    __shared__ unsigned short As[BM][KPAD];   // 5 KB
    __shared__ unsigned short Bs[BN][KPAD];   // 5 KB
    __shared__ int   r_lds[BM];
    __shared__ float w_lds[BM];

    const int tid = threadIdx.x;
    const int base = e * T_TOK;
    if (tid < BM) {
        const int m = m0 + tid;
        int r = -1; float w = 0.0f;
        if (m < n_e) { r = row_list[base + m]; w = wgt_list[base + m]; }
        r_lds[tid] = r; w_lds[tid] = w;
    }
    __syncthreads();

    const int ar = tid >> 2;
    const int ac = (tid & 3) * 8;
    const int arow = r_lds[ar];
    const unsigned short* ap =
        act + (size_t)(arow < 0 ? 0 : arow) * IDIM + ks + ac;
    unsigned short* Adst = &As[0][0] + ar * KPAD + ac;
    const unsigned short* bsrc = dwp + (size_t)(n0 + ar) * IDIM + ks + ac;
    unsigned short* Bdst = &Bs[0][0] + ar * KPAD + ac;

    const int wv = tid >> 6, lane = tid & 63;
    const int wm = (wv & 1) * 32, wn = (wv >> 1) * 32;
    const int l16 = lane & 15, quad = lane >> 4;

    f32x4 acc[2][2];
    const f32x4 zero = {0.0f, 0.0f, 0.0f, 0.0f};
#pragma unroll
    for (int i = 0; i < 2; ++i)
#pragma unroll
        for (int j = 0; j < 2; ++j) acc[i][j] = zero;

    uint4 PA = {0, 0, 0, 0}, PB;
    if (arow >= 0) PA = *(const uint4*)(ap);
    PB = *(const uint4*)(bsrc);

    for (int k0 = 0; k0 < DK_HALF; k0 += BK) {
        __syncthreads();
        *(uint4*)Adst = PA;
        *(uint4*)Bdst = PB;
        __syncthreads();

        const int kn = k0 + BK;
        if (kn < DK_HALF) {
            if (arow >= 0) PA = *(const uint4*)(ap + kn);
            PB = *(const uint4*)(bsrc + kn);
        }

        bf16x8 af[2], bfr[2];
#pragma unroll
        for (int i = 0; i < 2; ++i)
            af[i] = *(const bf16x8*)&As[wm + i * 16 + l16][quad * 8];
#pragma unroll
        for (int j = 0; j < 2; ++j)
            bfr[j] = *(const bf16x8*)&Bs[wn + j * 16 + l16][quad * 8];
#pragma unroll
        for (int i = 0; i < 2; ++i)
#pragma unroll
            for (int j = 0; j < 2; ++j)
                acc[i][j] = __builtin_amdgcn_mfma_f32_16x16x32_bf16(
                    af[i], bfr[j], acc[i][j], 0, 0, 0);
    }

#pragma unroll
    for (int j = 0; j < 2; ++j) {
        const int nl = n0 + wn + j * 16 + l16;
        const float bv = (sk == 0) ? dbp[nl] : 0.0f;
#pragma unroll
        for (int i = 0; i < 2; ++i) {
#pragma unroll
            for (int ii = 0; ii < 4; ++ii) {
                const int ml = wm + i * 16 + quad * 4 + ii;
                const int rr = r_lds[ml];
                if (rr >= 0)
                    y2s[(size_t)rr * HDIM + nl] = w_lds[ml] * (acc[i][j][ii] + bv);
            }
        }
    }
}

// --------------------------------------------------------------- combine ----
__global__ __launch_bounds__(256) void combine_kernel(
    const float* __restrict__ y2, float* __restrict__ out)
{
    const int idx = (blockIdx.x * 256 + threadIdx.x) * 4;   // < T*H
    const int t = idx >> 10;           // HDIM == 1024
    const int h = idx & 1023;
    const float* y2b = y2 + (size_t)2 * T_TOK * HDIM;
    const float4 a0 = *(const float4*)(y2  + ((size_t)2 * t) * HDIM + h);
    const float4 a1 = *(const float4*)(y2  + ((size_t)2 * t + 1) * HDIM + h);
    const float4 b0 = *(const float4*)(y2b + ((size_t)2 * t) * HDIM + h);
    const float4 b1 = *(const float4*)(y2b + ((size_t)2 * t + 1) * HDIM + h);
    float4 o;
    o.x = a0.x + a1.x + b0.x + b1.x;
    o.y = a0.y + a1.y + b0.y + b1.y;
    o.z = a0.z + a1.z + b0.z + b1.z;
    o.w = a0.w + a1.w + b0.w + b1.w;
    *(float4*)(out + idx) = o;
}

// ---------------------------------------------------------------- launch ----
extern "C" void kernel_launch(void* const* d_in, const int* in_sizes, int n_in,
                              void* d_out, int out_size, void* d_ws, size_t ws_size,
                              hipStream_t stream)
{
    const float* x      = (const float*)d_in[0];
    const float* rw     = (const float*)d_in[1];
    const float* gate_w = (const float*)d_in[2];
    const float* up_w   = (const float*)d_in[3];
    const float* down_w = (const float*)d_in[4];
    const float* gate_b = (const float*)d_in[5];
    const float* up_b   = (const float*)d_in[6];
    const float* down_b = (const float*)d_in[7];
    float* out = (float*)d_out;

    // workspace layout (~85 MB; y2[2 slices, 32 MB] aliases gwt+uwt,
    // which are dead after gateup)
    char* ws = (char*)d_ws;
    size_t off = 0;
    int*   counts   = (int*)(ws + off);  off += 256;
    int*   tok_list = (int*)(ws + off);  off += 65536;
    float* wgt_list = (float*)(ws + off); off += 65536;
    int*   row_list = (int*)(ws + off);  off += 65536;
    int*   sel      = (int*)(ws + off);  off += T_TOK * 4;
    float* w1arr    = (float*)(ws + off); off += T_TOK * 4;
    unsigned short* x_bf = (unsigned short*)(ws + off); off += (size_t)T_TOK * HDIM * 2;       // 4 MB
    unsigned short* act  = (unsigned short*)(ws + off); off += (size_t)2 * T_TOK * IDIM * 2;   // 11.5 MB
    unsigned short* dwt  = (unsigned short*)(ws + off); off += (size_t)NEXP * IDIM * HDIM * 2; // 23 MB
    unsigned short* gwt  = (unsigned short*)(ws + off); off += (size_t)NEXP * IDIM * HDIM * 2; // 23 MB
    unsigned short* uwt  = (unsigned short*)(ws + off);                                        // 23 MB
    float* y2 = (float*)gwt;   // 2 x 16 MB slices, reused after gateup

    wtrans_all_kernel<<<dim3(176, 1, 24), 256, 0, stream>>>(
        gate_w, up_w, down_w, gwt, uwt, dwt);

    router_compute_kernel<<<T_TOK / 4, 256, 0, stream>>>(x, rw, sel, w1arr, x_bf);

    router_scatter_kernel<<<1, 1024, 0, stream>>>(
        sel, w1arr, counts, tok_list, wgt_list, row_list);

    gateup_kernel<<<8 * GU_NT * GU_MT, 256, 0, stream>>>(
        x_bf, gwt, uwt, gate_b, up_b, counts, tok_list, row_list, act);

    down_kernel<<<8 * 2 * DN_NT * DN_MT, 256, 0, stream>>>(
        act, dwt, down_b, counts, wgt_list, row_list, y2);

    combine_kernel<<<(T_TOK * HDIM / 4) / 256, 256, 0, stream>>>(y2, out);
}

// Round 5
// 300.063 us; speedup vs baseline: 1.0059x; 1.0059x over previous
//
#include <hip/hip_runtime.h>

// DeepseekV3MoEToA2AAdapter: T=2048 tokens, H=1024, E=8, I=1408, top-2.
// fp32 I/O. NO weight pre-pass: GEMMs read fp32 weights directly and do the
// cast+transpose in LDS staging (coalesced [BK][BN] fp32 reads -> bf16
// [BN][KPAD] LDS). R0-proven 256-thread 4-wave MFMA structure (BM=128,
// BK=32, acc[4][2]); atomic-free router; non-atomic split-K down + combine.
#define T_TOK 2048
#define HDIM  1024
#define NEXP  8
#define IDIM  1408

#define BM 128
#define BN 64
#define BK 32
#define KPAD 40     // bf16 elems; 80 B rows, frag reads 2-way (free)
#define MT_SLOTS 16
#define GU_NT 22    // IDIM / BN
#define DN_NT 16    // HDIM / BN
#define DK_HALF 704 // IDIM / 2 (split-K for down)

typedef __attribute__((ext_vector_type(8))) short bf16x8;
typedef __attribute__((ext_vector_type(4))) float f32x4;

static __device__ __forceinline__ unsigned short f2bf(float f) {
    union { float f; unsigned u; } a; a.f = f;
    return (unsigned short)((a.u + 0x7fffu + ((a.u >> 16) & 1u)) >> 16);
}

// ------------------------------------------- router pass 1: compute ---------
// One wave per token; fp64 ladder (robust top-2 ordering); fused x->bf16.
__global__ __launch_bounds__(256) void router_compute_kernel(
    const float* __restrict__ x,        // [T, H]
    const float* __restrict__ rw,       // [H, E]
    int*   __restrict__ sel,            // [T]
    float* __restrict__ w1arr,          // [T]
    unsigned short* __restrict__ xb)    // [T, H] bf16
{
    __shared__ float rwT[NEXP][HDIM];   // 32 KB
    const int tid = threadIdx.x;
#pragma unroll
    for (int p = 0; p < 4; ++p) {
        const int h = tid + 256 * p;
        const float4 a = *(const float4*)(rw + (size_t)h * 8);
        const float4 b = *(const float4*)(rw + (size_t)h * 8 + 4);
        rwT[0][h] = a.x; rwT[1][h] = a.y; rwT[2][h] = a.z; rwT[3][h] = a.w;
        rwT[4][h] = b.x; rwT[5][h] = b.y; rwT[6][h] = b.z; rwT[7][h] = b.w;
    }
    __syncthreads();

    const int wave = (blockIdx.x * blockDim.x + threadIdx.x) >> 6;
    const int lane = threadIdx.x & 63;
    if (wave >= T_TOK) return;
    const int t = wave;

    float xr[16];
    const float* xp = x + (size_t)t * HDIM;
#pragma unroll
    for (int i = 0; i < 16; ++i) xr[i] = xp[lane + 64 * i];

    unsigned short* xbp = xb + (size_t)t * HDIM;
#pragma unroll
    for (int i = 0; i < 16; ++i) xbp[lane + 64 * i] = f2bf(xr[i]);

    double logits[NEXP];
#pragma unroll
    for (int e = 0; e < NEXP; ++e) {
        double s = 0.0;
#pragma unroll
        for (int i = 0; i < 16; ++i)
            s += (double)xr[i] * (double)rwT[e][lane + 64 * i];
#pragma unroll
        for (int off = 32; off > 0; off >>= 1)
            s += __shfl_down(s, off, 64);
        logits[e] = s;
    }

    if (lane == 0) {
        int e1 = 0;
        for (int e = 1; e < NEXP; ++e) if (logits[e] > logits[e1]) e1 = e;
        int e2 = -1;
        for (int e = 0; e < NEXP; ++e) {
            if (e == e1) continue;
            if (e2 < 0 || logits[e] > logits[e2]) e2 = e;
        }
        const double w1 = 1.0 / (1.0 + exp(logits[e2] - logits[e1]));
        sel[t]   = e1 | (e2 << 8);
        w1arr[t] = (float)w1;
    }
}

// ------------------------------------------- router pass 2: scatter ---------
__global__ __launch_bounds__(1024) void router_scatter_kernel(
    const int* __restrict__ sel, const float* __restrict__ w1arr,
    int* __restrict__ counts,
    int* __restrict__ tok_list, float* __restrict__ wgt_list,
    int* __restrict__ row_list)
{
    __shared__ int cnt[NEXP];
    const int tid = threadIdx.x;
    if (tid < NEXP) cnt[tid] = 0;
    __syncthreads();
    for (int t = tid; t < T_TOK; t += 1024) {
        const int s  = sel[t];
        const int e1 = s & 255, e2 = s >> 8;
        const float w1 = w1arr[t];
        const int p1 = atomicAdd(&cnt[e1], 1);
        tok_list[e1 * T_TOK + p1] = t;
        wgt_list[e1 * T_TOK + p1] = w1;
        row_list[e1 * T_TOK + p1] = 2 * t;
        const int p2 = atomicAdd(&cnt[e2], 1);
        tok_list[e2 * T_TOK + p2] = t;
        wgt_list[e2 * T_TOK + p2] = 1.0f - w1;
        row_list[e2 * T_TOK + p2] = 2 * t + 1;
    }
    __syncthreads();
    if (tid < NEXP) counts[tid] = cnt[tid];
}

// -------------------------------------------------- fused gate+up GEMM -----
// R0-proven structure + in-staging weight transpose: B tiles read as fp32
// [BK][BN] (coalesced rows of gate/up_proj), cast to bf16, stored transposed
// to LDS [BN][KPAD]. Per matrix 128 threads, 4k x 4n micro-tile per thread.
__global__ __launch_bounds__(256) void gateup_kernel(
    const unsigned short* __restrict__ xb,    // [T,H] bf16
    const float* __restrict__ gw,             // [E][H][I] fp32
    const float* __restrict__ uw,             // [E][H][I] fp32
    const float* __restrict__ gb, const float* __restrict__ ub,
    const int* __restrict__ counts,
    const int* __restrict__ tok_list,
    const int* __restrict__ row_list,
    unsigned short* __restrict__ act)         // [2T, IDIM] bf16
{
    const int flat = blockIdx.x;
    const int xcd  = flat & 7;
    const int q    = flat >> 3;
    const int mt   = q & 15;
    const int slot = q >> 4;
    const int P    = slot * 8 + xcd;   // 0..175 = (e, nt), fixed XCD per (e,nt)
    const int e    = P / GU_NT;
    const int nt   = P % GU_NT;
    const int n_e  = counts[e];
    const int m0   = mt * BM;
    if (m0 >= n_e) return;
    const int n0 = nt * BN;

    const float* gwp = gw + (size_t)e * HDIM * IDIM;
    const float* uwp = uw + (size_t)e * HDIM * IDIM;
    const float* gbp = gb + (size_t)e * IDIM;
    const float* ubp = ub + (size_t)e * IDIM;

    __shared__ unsigned short As[BM][KPAD];   // 10 KB
    __shared__ unsigned short Bg[BN][KPAD];   //  5 KB
    __shared__ unsigned short Bu[BN][KPAD];   //  5 KB
    __shared__ int gr_lds[BM];
    __shared__ int or_lds[BM];

    const int tid = threadIdx.x;
    const int base = e * T_TOK;
    if (tid < BM) {
        const int m = m0 + tid;
        int g = -1, o = -1;
        if (m < n_e) { g = tok_list[base + m]; o = row_list[base + m]; }
        gr_lds[tid] = g; or_lds[tid] = o;
    }
    __syncthreads();

    // A staging (R0): 128 rows x 2 halves of 16 bf16
    const int ar = tid >> 1;
    const int ac = (tid & 1) * 16;
    const int arow = gr_lds[ar];
    const unsigned short* ap = xb + (size_t)(arow < 0 ? 0 : arow) * HDIM;
    // B staging: tid<128 -> gate, else up. 4k x 4n fp32 micro-tile / thread.
    const int u  = tid & 127;
    const int kq = (u >> 4) * 4;        // 0..28
    const int nc = (u & 15) * 4;        // 0..60
    const float* bp =
        ((tid >> 7) ? uwp : gwp) + (size_t)kq * IDIM + n0 + nc;
    unsigned short* Bb = ((tid >> 7) ? &Bu[0][0] : &Bg[0][0]);

    const int wv = tid >> 6, lane = tid & 63;
    const int wm = (wv & 1) * 64, wn = (wv >> 1) * 32;
    const int l16 = lane & 15, quad = lane >> 4;

    f32x4 accg[4][2], accu[4][2];
    const f32x4 zero = {0.0f, 0.0f, 0.0f, 0.0f};
#pragma unroll
    for (int i = 0; i < 4; ++i)
#pragma unroll
        for (int j = 0; j < 2; ++j) { accg[i][j] = zero; accu[i][j] = zero; }

    uint4 PA0 = {0,0,0,0}, PA1 = {0,0,0,0};
    float4 PB0, PB1, PB2, PB3;
    if (arow >= 0) {
        PA0 = *(const uint4*)(ap + ac);
        PA1 = *(const uint4*)(ap + ac + 8);
    }
    PB0 = *(const float4*)(bp);
    PB1 = *(const float4*)(bp + IDIM);
    PB2 = *(const float4*)(bp + 2 * IDIM);
    PB3 = *(const float4*)(bp + 3 * IDIM);

    for (int k0 = 0; k0 < HDIM; k0 += BK) {
        __syncthreads();
        *(uint4*)&As[ar][ac]     = PA0;
        *(uint4*)&As[ar][ac + 8] = PA1;
#pragma unroll
        for (int i = 0; i < 4; ++i) {
            ushort4 w;
            w.x = f2bf(((const float*)&PB0)[i]);
            w.y = f2bf(((const float*)&PB1)[i]);
            w.z = f2bf(((const float*)&PB2)[i]);
            w.w = f2bf(((const float*)&PB3)[i]);
            *(ushort4*)(Bb + (size_t)(nc + i) * KPAD + kq) = w;
        }
        __syncthreads();

        const int kn = k0 + BK;
        if (kn < HDIM) {
            if (arow >= 0) {
                PA0 = *(const uint4*)(ap + kn + ac);
                PA1 = *(const uint4*)(ap + kn + ac + 8);
            }
            const float* bq = bp + (size_t)kn * IDIM;
            PB0 = *(const float4*)(bq);
            PB1 = *(const float4*)(bq + IDIM);
            PB2 = *(const float4*)(bq + 2 * IDIM);
            PB3 = *(const float4*)(bq + 3 * IDIM);
        }

        bf16x8 af[4], bgf[2], buf_[2];
#pragma unroll
        for (int i = 0; i < 4; ++i)
            af[i] = *(const bf16x8*)&As[wm + i * 16 + l16][quad * 8];
#pragma unroll
        for (int j = 0; j < 2; ++j) {
            bgf[j]  = *(const bf16x8*)&Bg[wn + j * 16 + l16][quad * 8];
            buf_[j] = *(const bf16x8*)&Bu[wn + j * 16 + l16][quad * 8];
        }
#pragma unroll
        for (int i = 0; i < 4; ++i)
#pragma unroll
            for (int j = 0; j < 2; ++j) {
                accg[i][j] = __builtin_amdgcn_mfma_f32_16x16x32_bf16(
                    af[i], bgf[j], accg[i][j], 0, 0, 0);
                accu[i][j] = __builtin_amdgcn_mfma_f32_16x16x32_bf16(
                    af[i], buf_[j], accu[i][j], 0, 0, 0);
            }
    }

    // epilogue: silu(g)*u -> bf16 act
#pragma unroll
    for (int j = 0; j < 2; ++j) {
        const int nl = n0 + wn + j * 16 + l16;
        const float gbv = gbp[nl];
        const float ubv = ubp[nl];
#pragma unroll
        for (int i = 0; i < 4; ++i) {
#pragma unroll
            for (int ii = 0; ii < 4; ++ii) {
                const int ml = wm + i * 16 + quad * 4 + ii;
                const int orow = or_lds[ml];
                if (orow >= 0) {
                    const float g = accg[i][j][ii] + gbv;
                    const float uu = accu[i][j][ii] + ubv;
                    act[(size_t)orow * IDIM + nl] =
                        f2bf(g * uu / (1.0f + __expf(-g)));
                }
            }
        }
    }
}

// ------------------------------------------------------- down-proj GEMM ----
// Split-K=2, NON-ATOMIC; B tile read fp32 [BK][BN] from down_proj directly,
// cast+transposed in staging (tid<128, 4k x 4n micro-tile).
__global__ __launch_bounds__(256) void down_kernel(
    const unsigned short* __restrict__ act,   // [2T, IDIM] bf16
    const float* __restrict__ dw,             // [E][I][H] fp32
    const float* __restrict__ db,
    const int* __restrict__ counts,
    const float* __restrict__ wgt_list,
    const int* __restrict__ row_list,
    float* __restrict__ y2)                   // [2][2T, HDIM] fp32
{
    const int flat = blockIdx.x;
    const int xcd  = flat & 7;
    const int q    = flat >> 3;
    const int mt   = q & 15;
    const int slot = q >> 4;
    const int P    = slot * 8 + xcd;   // 0..255 = (sk, e, nt)
    const int sk   = P & 1;
    const int en   = P >> 1;
    const int e    = en >> 4;
    const int nt   = en & 15;
    const int n_e  = counts[e];
    const int m0   = mt * BM;
    if (m0 >= n_e) return;
    const int n0 = nt * BN;
    const int ks = sk * DK_HALF;
    float* y2s = y2 + (size_t)sk * 2 * T_TOK * HDIM;

    const float* dwp = dw + (size_t)e * IDIM * HDIM;
    const float* dbp = db + (size_t)e * HDIM;

    __shared__ unsigned short As[BM][KPAD];   // 10 KB
    __shared__ unsigned short Bs[BN][KPAD];   //  5 KB
    __shared__ int   r_lds[BM];
    __shared__ float w_lds[BM];

    const int tid = threadIdx.x;
    const int base = e * T_TOK;
    if (tid < BM) {
        const int m = m0 + tid;
        int r = -1; float w = 0.0f;
        if (m < n_e) { r = row_list[base + m]; w = wgt_list[base + m]; }
        r_lds[tid] = r; w_lds[tid] = w;
    }
    __syncthreads();

    const int ar = tid >> 1;
    const int ac = (tid & 1) * 16;
    const int arow = r_lds[ar];
    const unsigned short* ap = act + (size_t)(arow < 0 ? 0 : arow) * IDIM + ks;
    const bool hasB = tid < 128;
    const int kq = ((tid & 127) >> 4) * 4;   // 0..28
    const int nc = (tid & 15) * 4;           // 0..60
    const float* bp = dwp + (size_t)(ks + kq) * HDIM + n0 + nc;

    const int wv = tid >> 6, lane = tid & 63;
    const int wm = (wv & 1) * 64, wn = (wv >> 1) * 32;
    const int l16 = lane & 15, quad = lane >> 4;

    f32x4 acc[4][2];
    const f32x4 zero = {0.0f, 0.0f, 0.0f, 0.0f};
#pragma unroll
    for (int i = 0; i < 4; ++i)
#pragma unroll
        for (int j = 0; j < 2; ++j) acc[i][j] = zero;

    uint4 PA0 = {0,0,0,0}, PA1 = {0,0,0,0};
    float4 PB0 = {0,0,0,0}, PB1 = {0,0,0,0}, PB2 = {0,0,0,0}, PB3 = {0,0,0,0};
    if (arow >= 0) {
        PA0 = *(const uint4*)(ap + ac);
        PA1 = *(const uint4*)(ap + ac + 8);
    }
    if (hasB) {
        PB0 = *(const float4*)(bp);
        PB1 = *(const float4*)(bp + HDIM);
        PB2 = *(const float4*)(bp + 2 * HDIM);
        PB3 = *(const float4*)(bp + 3 * HDIM);
    }

    for (int k0 = 0; k0 < DK_HALF; k0 += BK) {
        __syncthreads();
        *(uint4*)&As[ar][ac]     = PA0;
        *(uint4*)&As[ar][ac + 8] = PA1;
        if (hasB) {
#pragma unroll
            for (int i = 0; i < 4; ++i) {
                ushort4 w;
                w.x = f2bf(((const float*)&PB0)[i]);
                w.y = f2bf(((const float*)&PB1)[i]);
                w.z = f2bf(((const float*)&PB2)[i]);
                w.w = f2bf(((const float*)&PB3)[i]);
                *(ushort4*)(&Bs[0][0] + (size_t)(nc + i) * KPAD + kq) = w;
            }
        }
        __syncthreads();

        const int kn = k0 + BK;
        if (kn < DK_HALF) {
            if (arow >= 0) {
                PA0 = *(const uint4*)(ap + kn + ac);
                PA1 = *(const uint4*)(ap + kn + ac + 8);
            }
            if (hasB) {
                const float* bq = bp + (size_t)kn * HDIM;
                PB0 = *(const float4*)(bq);
                PB1 = *(const float4*)(bq + HDIM);
                PB2 = *(const float4*)(bq + 2 * HDIM);
                PB3 = *(const float4*)(bq + 3 * HDIM);
            }
        }

        bf16x8 af[4], bfr[2];
#pragma unroll
        for (int i = 0; i < 4; ++i)
            af[i] = *(const bf16x8*)&As[wm + i * 16 + l16][quad * 8];
#pragma unroll
        for (int j = 0; j < 2; ++j)
            bfr[j] = *(const bf16x8*)&Bs[wn + j * 16 + l16][quad * 8];
#pragma unroll
        for (int i = 0; i < 4; ++i)
#pragma unroll
            for (int j = 0; j < 2; ++j)
                acc[i][j] = __builtin_amdgcn_mfma_f32_16x16x32_bf16(
                    af[i], bfr[j], acc[i][j], 0, 0, 0);
    }

#pragma unroll
    for (int j = 0; j < 2; ++j) {
        const int nl = n0 + wn + j * 16 + l16;
        const float bv = (sk == 0) ? dbp[nl] : 0.0f;
#pragma unroll
        for (int i = 0; i < 4; ++i) {
#pragma unroll
            for (int ii = 0; ii < 4; ++ii) {
                const int ml = wm + i * 16 + quad * 4 + ii;
                const int rr = r_lds[ml];
                if (rr >= 0)
                    y2s[(size_t)rr * HDIM + nl] = w_lds[ml] * (acc[i][j][ii] + bv);
            }
        }
    }
}

// --------------------------------------------------------------- combine ----
__global__ __launch_bounds__(256) void combine_kernel(
    const float* __restrict__ y2, float* __restrict__ out)
{
    const int idx = (blockIdx.x * 256 + threadIdx.x) * 4;   // < T*H
    const int t = idx >> 10;           // HDIM == 1024
    const int h = idx & 1023;
    const float* y2b = y2 + (size_t)2 * T_TOK * HDIM;
    const float4 a0 = *(const float4*)(y2  + ((size_t)2 * t) * HDIM + h);
    const float4 a1 = *(const float4*)(y2  + ((size_t)2 * t + 1) * HDIM + h);
    const float4 b0 = *(const float4*)(y2b + ((size_t)2 * t) * HDIM + h);
    const float4 b1 = *(const float4*)(y2b + ((size_t)2 * t + 1) * HDIM + h);
    float4 o;
    o.x = a0.x + a1.x + b0.x + b1.x;
    o.y = a0.y + a1.y + b0.y + b1.y;
    o.z = a0.z + a1.z + b0.z + b1.z;
    o.w = a0.w + a1.w + b0.w + b1.w;
    *(float4*)(out + idx) = o;
}

// ---------------------------------------------------------------- launch ----
extern "C" void kernel_launch(void* const* d_in, const int* in_sizes, int n_in,
                              void* d_out, int out_size, void* d_ws, size_t ws_size,
                              hipStream_t stream)
{
    const float* x      = (const float*)d_in[0];
    const float* rw     = (const float*)d_in[1];
    const float* gate_w = (const float*)d_in[2];
    const float* up_w   = (const float*)d_in[3];
    const float* down_w = (const float*)d_in[4];
    const float* gate_b = (const float*)d_in[5];
    const float* up_b   = (const float*)d_in[6];
    const float* down_b = (const float*)d_in[7];
    float* out = (float*)d_out;

    // workspace layout (~48 MB; no weight transposes any more)
    char* ws = (char*)d_ws;
    size_t off = 0;
    int*   counts   = (int*)(ws + off);  off += 256;
    int*   tok_list = (int*)(ws + off);  off += 65536;
    float* wgt_list = (float*)(ws + off); off += 65536;
    int*   row_list = (int*)(ws + off);  off += 65536;
    int*   sel      = (int*)(ws + off);  off += T_TOK * 4;
    float* w1arr    = (float*)(ws + off); off += T_TOK * 4;
    unsigned short* x_bf = (unsigned short*)(ws + off); off += (size_t)T_TOK * HDIM * 2;       // 4 MB
    unsigned short* act  = (unsigned short*)(ws + off); off += (size_t)2 * T_TOK * IDIM * 2;   // 11.5 MB
    float* y2 = (float*)(ws + off);   // 2 x 16 MB split-K slices

    router_compute_kernel<<<T_TOK / 4, 256, 0, stream>>>(x, rw, sel, w1arr, x_bf);

    router_scatter_kernel<<<1, 1024, 0, stream>>>(
        sel, w1arr, counts, tok_list, wgt_list, row_list);

    gateup_kernel<<<8 * GU_NT * MT_SLOTS, 256, 0, stream>>>(
        x_bf, gate_w, up_w, gate_b, up_b, counts, tok_list, row_list, act);

    down_kernel<<<2 * 8 * DN_NT * MT_SLOTS, 256, 0, stream>>>(
        act, down_w, down_b, counts, wgt_list, row_list, y2);

    combine_kernel<<<(T_TOK * HDIM / 4) / 256, 256, 0, stream>>>(y2, out);
}

// Round 6
// 277.469 us; speedup vs baseline: 1.0879x; 1.0814x over previous
//
#include <hip/hip_runtime.h>

// DeepseekV3MoEToA2AAdapter: T=2048 tokens, H=1024, E=8, I=1408, top-2.
// fp32 I/O. R0-proven kernel bodies; NEW: block-range fusion to overlap
// independent phases on one stream:
//   prep      = router_compute (blocks [0,512)) || wtrans gate/up (tail)
//   gateup_wd = gateup (blocks [0,2816))        || wtrans down   (tail)
// (dwt produced inside gateup_wd is consumed by down, next launch -> safe.)
// Atomic-free router; non-atomic split-K down + 4-way combine.
#define T_TOK 2048
#define HDIM  1024
#define NEXP  8
#define IDIM  1408

#define BM 128
#define BN 64
#define BK 32
#define KPAD 40     // bf16 elems; 80 B rows, 16B-aligned
#define MT_SLOTS 16
#define GU_NT 22    // IDIM / BN
#define DN_NT 16    // HDIM / BN
#define DK_HALF 704 // IDIM / 2 (split-K for down)

#define GU_BLOCKS   (8 * GU_NT * MT_SLOTS)   // 2816
#define PREP_RTR    512                      // router blocks
#define PREP_GRID   (PREP_RTR + 16 * 176)    // 3328
#define GUWD_GRID   (GU_BLOCKS + 8 * 176)    // 4224

typedef __attribute__((ext_vector_type(8))) short bf16x8;
typedef __attribute__((ext_vector_type(4))) float f32x4;

static __device__ __forceinline__ unsigned short f2bf(float f) {
    union { float f; unsigned u; } a; a.f = f;
    return (unsigned short)((a.u + 0x7fffu + ((a.u >> 16) & 1u)) >> 16);
}

// ---------------------------------------------------------------- prep ------
// blocks [0,512): router pass 1 (one wave per token; fp64 ladder; x->bf16).
// blocks [512,3328): gate/up weight cast+transpose via LDS (R0 wtrans body).
__global__ __launch_bounds__(256) void prep_kernel(
    const float* __restrict__ x,        // [T, H]
    const float* __restrict__ rw,       // [H, E]
    const float* __restrict__ gw,       // [E][H][I] fp32
    const float* __restrict__ uw,       // [E][H][I] fp32
    int*   __restrict__ sel,            // [T]
    float* __restrict__ w1arr,          // [T]
    unsigned short* __restrict__ xb,    // [T, H] bf16
    unsigned short* __restrict__ gwt,   // [E][I][H] bf16
    unsigned short* __restrict__ uwt)   // [E][I][H] bf16
{
    __shared__ __align__(16) char smem[32768];
    const int tid = threadIdx.x;
    const int bx  = blockIdx.x;

    if (bx < PREP_RTR) {
        // ------------------------------ router compute ------------------
        float (*rwT)[HDIM] = (float (*)[HDIM])smem;   // 32 KB
#pragma unroll
        for (int p = 0; p < 4; ++p) {
            const int h = tid + 256 * p;
            const float4 a = *(const float4*)(rw + (size_t)h * 8);
            const float4 b = *(const float4*)(rw + (size_t)h * 8 + 4);
            rwT[0][h] = a.x; rwT[1][h] = a.y; rwT[2][h] = a.z; rwT[3][h] = a.w;
            rwT[4][h] = b.x; rwT[5][h] = b.y; rwT[6][h] = b.z; rwT[7][h] = b.w;
        }
        __syncthreads();

        const int t    = bx * 4 + (tid >> 6);
        const int lane = tid & 63;
        if (t >= T_TOK) return;

        float xr[16];
        const float* xp = x + (size_t)t * HDIM;
#pragma unroll
        for (int i = 0; i < 16; ++i) xr[i] = xp[lane + 64 * i];

        unsigned short* xbp = xb + (size_t)t * HDIM;
#pragma unroll
        for (int i = 0; i < 16; ++i) xbp[lane + 64 * i] = f2bf(xr[i]);

        double logits[NEXP];
#pragma unroll
        for (int e = 0; e < NEXP; ++e) {
            double s = 0.0;
#pragma unroll
            for (int i = 0; i < 16; ++i)
                s += (double)xr[i] * (double)rwT[e][lane + 64 * i];
#pragma unroll
            for (int off = 32; off > 0; off >>= 1)
                s += __shfl_down(s, off, 64);
            logits[e] = s;
        }

        if (lane == 0) {
            int e1 = 0;
            for (int e = 1; e < NEXP; ++e) if (logits[e] > logits[e1]) e1 = e;
            int e2 = -1;
            for (int e = 0; e < NEXP; ++e) {
                if (e == e1) continue;
                if (e2 < 0 || logits[e] > logits[e2]) e2 = e;
            }
            const double w1 = 1.0 / (1.0 + exp(logits[e2] - logits[e1]));
            sel[t]   = e1 | (e2 << 8);
            w1arr[t] = (float)w1;
        }
    } else {
        // ------------------------------ wtrans gate/up ------------------
        const int idx = bx - PREP_RTR;
        const int z   = idx / 176;          // 0..15
        const int b   = idx - z * 176;      // 0..175
        const int e   = z & 7;
        const float* src = (z < 8 ? gw : uw) + (size_t)e * HDIM * IDIM;
        unsigned short* dst =
            (z < 8 ? gwt : uwt) + (size_t)e * (size_t)IDIM * HDIM;
        const int nb = b % 11, kb = b / 11;  // 11 n-tiles x 16 k-tiles
        const int k0 = kb * 64, n0 = nb * 128;

        unsigned short (*tb)[66] = (unsigned short (*)[66])smem; // 16.9 KB

        const int lk = tid >> 5;            // 0..7
        const int ln = (tid & 31) * 4;      // 0..124
#pragma unroll
        for (int r = 0; r < 8; ++r) {
            const int k = r * 8 + lk;
            const float4 v =
                *(const float4*)(src + (size_t)(k0 + k) * IDIM + n0 + ln);
            tb[ln + 0][k] = f2bf(v.x);
            tb[ln + 1][k] = f2bf(v.y);
            tb[ln + 2][k] = f2bf(v.z);
            tb[ln + 3][k] = f2bf(v.w);
        }
        __syncthreads();

        const int wn = tid >> 3;            // 0..31
        const int wk = (tid & 7) * 8;       // 0..56
#pragma unroll
        for (int p = 0; p < 4; ++p) {
            const int n = p * 32 + wn;
            const unsigned* rp = (const unsigned*)&tb[n][wk];
            uint4 o;
            o.x = rp[0]; o.y = rp[1]; o.z = rp[2]; o.w = rp[3];
            *(uint4*)(dst + (size_t)(n0 + n) * HDIM + k0 + wk) = o;
        }
    }
}

// ------------------------------------------- router pass 2: scatter ---------
__global__ __launch_bounds__(1024) void router_scatter_kernel(
    const int* __restrict__ sel, const float* __restrict__ w1arr,
    int* __restrict__ counts,
    int* __restrict__ tok_list, float* __restrict__ wgt_list,
    int* __restrict__ row_list)
{
    __shared__ int cnt[NEXP];
    const int tid = threadIdx.x;
    if (tid < NEXP) cnt[tid] = 0;
    __syncthreads();
    for (int t = tid; t < T_TOK; t += 1024) {
        const int s  = sel[t];
        const int e1 = s & 255, e2 = s >> 8;
        const float w1 = w1arr[t];
        const int p1 = atomicAdd(&cnt[e1], 1);
        tok_list[e1 * T_TOK + p1] = t;
        wgt_list[e1 * T_TOK + p1] = w1;
        row_list[e1 * T_TOK + p1] = 2 * t;
        const int p2 = atomicAdd(&cnt[e2], 1);
        tok_list[e2 * T_TOK + p2] = t;
        wgt_list[e2 * T_TOK + p2] = 1.0f - w1;
        row_list[e2 * T_TOK + p2] = 2 * t + 1;
    }
    __syncthreads();
    if (tid < NEXP) counts[tid] = cnt[tid];
}

// -------------------------------- fused gate+up GEMM || wtrans(down) --------
// blocks [0,2816): R0 gateup body (BM=128, BK=32, 4 waves, acc[4][2]).
// blocks [2816,4224): down_proj cast+transpose (R0 wtrans body, K=I, N=H);
// overlaps the latency-bound GEMM with the BW-bound transpose. dwt is
// consumed only by down_kernel (next launch on the stream) -> no race.
__global__ __launch_bounds__(256) void gateup_wd_kernel(
    const unsigned short* __restrict__ xb,    // [T,H] bf16
    const unsigned short* __restrict__ gwt,   // [E][I][H] bf16
    const unsigned short* __restrict__ uwt,   // [E][I][H] bf16
    const float* __restrict__ gb, const float* __restrict__ ub,
    const int* __restrict__ counts,
    const int* __restrict__ tok_list,
    const int* __restrict__ row_list,
    unsigned short* __restrict__ act,         // [2T, IDIM] bf16
    const float* __restrict__ dw,             // [E][I][H] fp32
    unsigned short* __restrict__ dwt)         // [E][H][I] bf16
{
    __shared__ __align__(16) char smem[21504];
    const int tid  = threadIdx.x;
    const int flat = blockIdx.x;

    if (flat >= GU_BLOCKS) {
        // ------------------------------ wtrans down ---------------------
        const int idx = flat - GU_BLOCKS;
        const int e   = idx / 176;
        const int b   = idx - e * 176;
        const float* src = dw + (size_t)e * IDIM * HDIM;   // [I][H] fp32
        unsigned short* dst = dwt + (size_t)e * (size_t)HDIM * IDIM;
        const int nb = b & 7, kb = b >> 3;   // 8 n-tiles x 22 k-tiles
        const int k0 = kb * 64, n0 = nb * 128;

        unsigned short (*tb)[66] = (unsigned short (*)[66])smem;

        const int lk = tid >> 5;
        const int ln = (tid & 31) * 4;
#pragma unroll
        for (int r = 0; r < 8; ++r) {
            const int k = r * 8 + lk;
            const float4 v =
                *(const float4*)(src + (size_t)(k0 + k) * HDIM + n0 + ln);
            tb[ln + 0][k] = f2bf(v.x);
            tb[ln + 1][k] = f2bf(v.y);
            tb[ln + 2][k] = f2bf(v.z);
            tb[ln + 3][k] = f2bf(v.w);
        }
        __syncthreads();

        const int wn = tid >> 3;
        const int wk = (tid & 7) * 8;
#pragma unroll
        for (int p = 0; p < 4; ++p) {
            const int n = p * 32 + wn;
            const unsigned* rp = (const unsigned*)&tb[n][wk];
            uint4 o;
            o.x = rp[0]; o.y = rp[1]; o.z = rp[2]; o.w = rp[3];
            *(uint4*)(dst + (size_t)(n0 + n) * IDIM + k0 + wk) = o;
        }
        return;
    }

    // ---------------------------------- gateup (R0 body) ----------------
    unsigned short (*As)[KPAD] = (unsigned short (*)[KPAD])smem;          // 10240
    unsigned short (*Bg)[KPAD] = (unsigned short (*)[KPAD])(smem + 10240); // 5120
    unsigned short (*Bu)[KPAD] = (unsigned short (*)[KPAD])(smem + 15360); // 5120
    int* gr_lds = (int*)(smem + 20480);
    int* or_lds = (int*)(smem + 20992);

    const int xcd  = flat & 7;
    const int q    = flat >> 3;
    const int mt   = q & 15;
    const int slot = q >> 4;
    const int P    = slot * 8 + xcd;   // 0..175 = (e, nt), fixed XCD per (e,nt)
    const int e    = P / GU_NT;
    const int nt   = P % GU_NT;
    const int n_e  = counts[e];
    const int m0   = mt * BM;
    if (m0 >= n_e) return;
    const int n0 = nt * BN;

    const unsigned short* gwp = gwt + (size_t)e * IDIM * HDIM;
    const unsigned short* uwp = uwt + (size_t)e * IDIM * HDIM;
    const float* gbp = gb + (size_t)e * IDIM;
    const float* ubp = ub + (size_t)e * IDIM;

    const int base = e * T_TOK;
    if (tid < BM) {
        const int m = m0 + tid;
        int g = -1, o = -1;
        if (m < n_e) { g = tok_list[base + m]; o = row_list[base + m]; }
        gr_lds[tid] = g; or_lds[tid] = o;
    }
    __syncthreads();

    const int ar = tid >> 1;
    const int ac = (tid & 1) * 16;
    const int arow = gr_lds[ar];
    const unsigned short* ap = xb + (size_t)(arow < 0 ? 0 : arow) * HDIM;
    const int u   = tid & 127;
    const int brow = u >> 1;
    const int bch  = (u & 1) * 16;
    const unsigned short* bsrc =
        ((tid >> 7) ? uwp : gwp) + (size_t)(n0 + brow) * HDIM + bch;
    unsigned short* Bdst =
        ((tid >> 7) ? &Bu[0][0] : &Bg[0][0]) + brow * KPAD + bch;

    const int wv = tid >> 6, lane = tid & 63;
    const int wm = (wv & 1) * 64, wn = (wv >> 1) * 32;
    const int l16 = lane & 15, quad = lane >> 4;

    f32x4 accg[4][2], accu[4][2];
    const f32x4 zero = {0.0f, 0.0f, 0.0f, 0.0f};
#pragma unroll
    for (int i = 0; i < 4; ++i)
#pragma unroll
        for (int j = 0; j < 2; ++j) { accg[i][j] = zero; accu[i][j] = zero; }

    uint4 PA0 = {0,0,0,0}, PA1 = {0,0,0,0}, PB0, PB1;
    if (arow >= 0) {
        PA0 = *(const uint4*)(ap + ac);
        PA1 = *(const uint4*)(ap + ac + 8);
    }
    PB0 = *(const uint4*)(bsrc);
    PB1 = *(const uint4*)(bsrc + 8);

    for (int k0 = 0; k0 < HDIM; k0 += BK) {
        __syncthreads();
        *(uint4*)&As[ar][ac]       = PA0;
        *(uint4*)&As[ar][ac + 8]   = PA1;
        *(uint4*)(Bdst)            = PB0;
        *(uint4*)(Bdst + 8)        = PB1;
        __syncthreads();

        const int kn = k0 + BK;
        if (kn < HDIM) {
            if (arow >= 0) {
                PA0 = *(const uint4*)(ap + kn + ac);
                PA1 = *(const uint4*)(ap + kn + ac + 8);
            }
            PB0 = *(const uint4*)(bsrc + kn);
            PB1 = *(const uint4*)(bsrc + kn + 8);
        }

        bf16x8 af[4], bgf[2], buf_[2];
#pragma unroll
        for (int i = 0; i < 4; ++i)
            af[i] = *(const bf16x8*)&As[wm + i * 16 + l16][quad * 8];
#pragma unroll
        for (int j = 0; j < 2; ++j) {
            bgf[j]  = *(const bf16x8*)&Bg[wn + j * 16 + l16][quad * 8];
            buf_[j] = *(const bf16x8*)&Bu[wn + j * 16 + l16][quad * 8];
        }
#pragma unroll
        for (int i = 0; i < 4; ++i)
#pragma unroll
            for (int j = 0; j < 2; ++j) {
                accg[i][j] = __builtin_amdgcn_mfma_f32_16x16x32_bf16(
                    af[i], bgf[j], accg[i][j], 0, 0, 0);
                accu[i][j] = __builtin_amdgcn_mfma_f32_16x16x32_bf16(
                    af[i], buf_[j], accu[i][j], 0, 0, 0);
            }
    }

    // epilogue: silu(g)*u -> bf16 act
#pragma unroll
    for (int j = 0; j < 2; ++j) {
        const int nl = n0 + wn + j * 16 + l16;
        const float gbv = gbp[nl];
        const float ubv = ubp[nl];
#pragma unroll
        for (int i = 0; i < 4; ++i) {
#pragma unroll
            for (int ii = 0; ii < 4; ++ii) {
                const int ml = wm + i * 16 + quad * 4 + ii;
                const int orow = or_lds[ml];
                if (orow >= 0) {
                    const float g = accg[i][j][ii] + gbv;
                    const float uu = accu[i][j][ii] + ubv;
                    act[(size_t)orow * IDIM + nl] =
                        f2bf(g * uu / (1.0f + __expf(-g)));
                }
            }
        }
    }
}

// ------------------------------------------------------- down-proj GEMM ----
// Split-K=2, NON-ATOMIC: slice sk writes plain stores into y2 + sk*(2T*H).
__global__ __launch_bounds__(256) void down_kernel(
    const unsigned short* __restrict__ act,   // [2T, IDIM] bf16
    const unsigned short* __restrict__ dwt,   // [E][H][I] bf16
    const float* __restrict__ db,
    const int* __restrict__ counts,
    const float* __restrict__ wgt_list,
    const int* __restrict__ row_list,
    float* __restrict__ y2)                   // [2][2T, HDIM] fp32
{
    const int flat = blockIdx.x;
    const int xcd  = flat & 7;
    const int q    = flat >> 3;
    const int mt   = q & 15;
    const int slot = q >> 4;
    const int P    = slot * 8 + xcd;   // 0..255 = (sk, e, nt)
    const int sk   = P & 1;
    const int en   = P >> 1;
    const int e    = en >> 4;
    const int nt   = en & 15;
    const int n_e  = counts[e];
    const int m0   = mt * BM;
    if (m0 >= n_e) return;
    const int n0 = nt * BN;
    const int ks = sk * DK_HALF;
    float* y2s = y2 + (size_t)sk * 2 * T_TOK * HDIM;

    const unsigned short* dwp = dwt + (size_t)e * HDIM * IDIM;
    const float* dbp = db + (size_t)e * HDIM;

    __shared__ unsigned short As[BM][KPAD];
    __shared__ unsigned short Bs[BN][KPAD];
    __shared__ int   r_lds[BM];
    __shared__ float w_lds[BM];

    const int tid = threadIdx.x;
    const int base = e * T_TOK;
    if (tid < BM) {
        const int m = m0 + tid;
        int r = -1; float w = 0.0f;
        if (m < n_e) { r = row_list[base + m]; w = wgt_list[base + m]; }
        r_lds[tid] = r; w_lds[tid] = w;
    }
    __syncthreads();

    const int ar = tid >> 1;
    const int ac = (tid & 1) * 16;
    const int arow = r_lds[ar];
    const unsigned short* ap = act + (size_t)(arow < 0 ? 0 : arow) * IDIM + ks;
    const int brow = tid >> 2;
    const int bch  = (tid & 3) * 8;
    const unsigned short* bsrc = dwp + (size_t)(n0 + brow) * IDIM + ks + bch;
    unsigned short* Bdst = &Bs[0][0] + brow * KPAD + bch;

    const int wv = tid >> 6, lane = tid & 63;
    const int wm = (wv & 1) * 64, wn = (wv >> 1) * 32;
    const int l16 = lane & 15, quad = lane >> 4;

    f32x4 acc[4][2];
    const f32x4 zero = {0.0f, 0.0f, 0.0f, 0.0f};
#pragma unroll
    for (int i = 0; i < 4; ++i)
#pragma unroll
        for (int j = 0; j < 2; ++j) acc[i][j] = zero;

    uint4 PA0 = {0,0,0,0}, PA1 = {0,0,0,0}, PB;
    if (arow >= 0) {
        PA0 = *(const uint4*)(ap + ac);
        PA1 = *(const uint4*)(ap + ac + 8);
    }
    PB = *(const uint4*)(bsrc);

    for (int k0 = 0; k0 < DK_HALF; k0 += BK) {
        __syncthreads();
        *(uint4*)&As[ar][ac]     = PA0;
        *(uint4*)&As[ar][ac + 8] = PA1;
        *(uint4*)(Bdst)          = PB;
        __syncthreads();

        const int kn = k0 + BK;
        if (kn < DK_HALF) {
            if (arow >= 0) {
                PA0 = *(const uint4*)(ap + kn + ac);
                PA1 = *(const uint4*)(ap + kn + ac + 8);
            }
            PB = *(const uint4*)(bsrc + kn);
        }

        bf16x8 af[4], bfr[2];
#pragma unroll
        for (int i = 0; i < 4; ++i)
            af[i] = *(const bf16x8*)&As[wm + i * 16 + l16][quad * 8];
#pragma unroll
        for (int j = 0; j < 2; ++j)
            bfr[j] = *(const bf16x8*)&Bs[wn + j * 16 + l16][quad * 8];
#pragma unroll
        for (int i = 0; i < 4; ++i)
#pragma unroll
            for (int j = 0; j < 2; ++j)
                acc[i][j] = __builtin_amdgcn_mfma_f32_16x16x32_bf16(
                    af[i], bfr[j], acc[i][j], 0, 0, 0);
    }

#pragma unroll
    for (int j = 0; j < 2; ++j) {
        const int nl = n0 + wn + j * 16 + l16;
        const float bv = (sk == 0) ? dbp[nl] : 0.0f;
#pragma unroll
        for (int i = 0; i < 4; ++i) {
#pragma unroll
            for (int ii = 0; ii < 4; ++ii) {
                const int ml = wm + i * 16 + quad * 4 + ii;
                const int rr = r_lds[ml];
                if (rr >= 0)
                    y2s[(size_t)rr * HDIM + nl] = w_lds[ml] * (acc[i][j][ii] + bv);
            }
        }
    }
}

// --------------------------------------------------------------- combine ----
__global__ __launch_bounds__(256) void combine_kernel(
    const float* __restrict__ y2, float* __restrict__ out)
{
    const int idx = (blockIdx.x * 256 + threadIdx.x) * 4;   // < T*H
    const int t = idx >> 10;           // HDIM == 1024
    const int h = idx & 1023;
    const float* y2b = y2 + (size_t)2 * T_TOK * HDIM;
    const float4 a0 = *(const float4*)(y2  + ((size_t)2 * t) * HDIM + h);
    const float4 a1 = *(const float4*)(y2  + ((size_t)2 * t + 1) * HDIM + h);
    const float4 b0 = *(const float4*)(y2b + ((size_t)2 * t) * HDIM + h);
    const float4 b1 = *(const float4*)(y2b + ((size_t)2 * t + 1) * HDIM + h);
    float4 o;
    o.x = a0.x + a1.x + b0.x + b1.x;
    o.y = a0.y + a1.y + b0.y + b1.y;
    o.z = a0.z + a1.z + b0.z + b1.z;
    o.w = a0.w + a1.w + b0.w + b1.w;
    *(float4*)(out + idx) = o;
}

// ---------------------------------------------------------------- launch ----
extern "C" void kernel_launch(void* const* d_in, const int* in_sizes, int n_in,
                              void* d_out, int out_size, void* d_ws, size_t ws_size,
                              hipStream_t stream)
{
    const float* x      = (const float*)d_in[0];
    const float* rw     = (const float*)d_in[1];
    const float* gate_w = (const float*)d_in[2];
    const float* up_w   = (const float*)d_in[3];
    const float* down_w = (const float*)d_in[4];
    const float* gate_b = (const float*)d_in[5];
    const float* up_b   = (const float*)d_in[6];
    const float* down_b = (const float*)d_in[7];
    float* out = (float*)d_out;

    // workspace layout (~85 MB; y2[2 slices, 32 MB] aliases gwt+uwt,
    // which are dead after gateup_wd)
    char* ws = (char*)d_ws;
    size_t off = 0;
    int*   counts   = (int*)(ws + off);  off += 256;
    int*   tok_list = (int*)(ws + off);  off += 65536;
    float* wgt_list = (float*)(ws + off); off += 65536;
    int*   row_list = (int*)(ws + off);  off += 65536;
    int*   sel      = (int*)(ws + off);  off += T_TOK * 4;
    float* w1arr    = (float*)(ws + off); off += T_TOK * 4;
    unsigned short* x_bf = (unsigned short*)(ws + off); off += (size_t)T_TOK * HDIM * 2;       // 4 MB
    unsigned short* act  = (unsigned short*)(ws + off); off += (size_t)2 * T_TOK * IDIM * 2;   // 11.5 MB
    unsigned short* dwt  = (unsigned short*)(ws + off); off += (size_t)NEXP * IDIM * HDIM * 2; // 23 MB
    unsigned short* gwt  = (unsigned short*)(ws + off); off += (size_t)NEXP * IDIM * HDIM * 2; // 23 MB
    unsigned short* uwt  = (unsigned short*)(ws + off);                                        // 23 MB
    float* y2 = (float*)gwt;   // 2 x 16 MB slices, reused after gateup_wd

    prep_kernel<<<PREP_GRID, 256, 0, stream>>>(
        x, rw, gate_w, up_w, sel, w1arr, x_bf, gwt, uwt);

    router_scatter_kernel<<<1, 1024, 0, stream>>>(
        sel, w1arr, counts, tok_list, wgt_list, row_list);

    gateup_wd_kernel<<<GUWD_GRID, 256, 0, stream>>>(
        x_bf, gwt, uwt, gate_b, up_b, counts, tok_list, row_list, act,
        down_w, dwt);

    down_kernel<<<2 * 8 * DN_NT * MT_SLOTS, 256, 0, stream>>>(
        act, dwt, down_b, counts, wgt_list, row_list, y2);

    combine_kernel<<<(T_TOK * HDIM / 4) / 256, 256, 0, stream>>>(y2, out);
}